// Round 4
// baseline (1017.428 us; speedup 1.0000x reference)
//
#include <hip/hip_runtime.h>

namespace {
constexpr int MD  = 4;
constexpr int BB  = 8, CCH = 128, HH = 96, WW = 192;
constexpr int TH  = 16, TW = 48, WPT = 12;      // tile 16 x 48, 12 px/thread
constexpr int CSPLIT = 2, CHB = CCH / CSPLIT;   // 64 channels per block
constexpr int KC  = 4;                           // channels per LDS chunk
constexpr int NCHUNK = CHB / KC;                 // 16 chunks per block
constexpr int SROWS = 18;                        // staged rows per rrset
constexpr int NJ  = 14;                          // logical f4 per row
constexpr int LJ  = 16;                          // padded f4 per row (XOR-safe)
constexpr int NTHR = 192;                        // 3 waves; wave = one disp row
constexpr int F4C = SROWS * NJ;                  // 252 f4 per channel
constexpr int F4K = KC * F4C;                    // 1008 per chunk
constexpr int PER = (F4K + NTHR - 1) / NTHR;     // 6 slots/thread
}

__global__ __launch_bounds__(NTHR, 2)
void corr81(const float* __restrict__ in0,
            const float* __restrict__ in1,
            float* __restrict__ out)
{
    const int tid  = threadIdx.x;
    const int wv   = tid >> 6;            // wave -> rr within rrset
    const int lane = tid & 63;
    const int g    = lane >> 2;           // h-row in tile (0..15)
    const int q    = lane & 3;            // w-group: owns w0+q*12 .. +11

    const int wt = blockIdx.x, ht = blockIdx.y, zz = blockIdx.z;
    const int chalf = zz / 24;            // C-half (0..1)
    const int rem   = zz % 24;
    const int b  = rem / 3, rs = rem % 3; // rs = rrset (disp rows rs*3..rs*3+2)
    const int w0 = wt * TW, h0 = ht * TH;
    const int rr   = rs * 3 + wv;         // displacement row 0..8
    const int rmin = rs * 3 - 4;          // first staged row offset vs h0

    __shared__ float4 lds[2][KC][SROWS][LJ];     // 36.9 KB, double-buffered

    const size_t plane = (size_t)HH * WW;
    const size_t img   = (size_t)CCH * plane;
    const float* in1b  = in1 + (size_t)b * img + (size_t)chalf * CHB * plane;
    const float* in0b  = in0 + (size_t)b * img + (size_t)chalf * CHB * plane;

    // ---- staging slots: s -> (ch, row, j) ----
    int  soff[PER];  int ldst[PER];  bool sok[PER];
    #pragma unroll
    for (int i = 0; i < PER; ++i) {
        const int s   = tid + i * NTHR;
        const int ch  = s / F4C;
        const int r2  = s % F4C;
        const int row = r2 / NJ;
        const int j   = r2 % NJ;
        const int hr  = h0 + rmin + row;
        const int wc  = w0 - 4 + 4 * j;
        sok[i]  = (s < F4K) && hr >= 0 && hr < HH && wc >= 0 && (wc + 3) < WW;
        soff[i] = ch * (int)plane + hr * WW + wc;
        const int js = (j & 8) | ((j ^ (row & 7)) & 7);    // XOR bank swizzle
        ldst[i] = (ch * SROWS + row) * LJ + js;
    }
    const bool svalid5 = (tid + (PER - 1) * NTHR) < F4K;

    // window read slots (thread-constant, swizzled)
    const int rowidx = g + wv;
    int js_[5];
    #pragma unroll
    for (int k = 0; k < 5; ++k) {
        const int jl = 3 * q + k;
        js_[k] = (jl & 8) | ((jl ^ (rowidx & 7)) & 7);
    }

    const float* pa = in0b + (size_t)(h0 + g) * WW + (w0 + q * WPT);

    float acc[9][WPT];
    #pragma unroll
    for (int cc = 0; cc < 9; ++cc)
        #pragma unroll
        for (int j = 0; j < WPT; ++j) acc[cc][j] = 0.f;

    // ---- prologue: chunk 0 into regs ----
    float4 stg[PER];
    #pragma unroll
    for (int i = 0; i < PER; ++i)
        stg[i] = sok[i] ? *(const float4*)(in1b + soff[i])
                        : make_float4(0.f, 0.f, 0.f, 0.f);

    for (int t = 0; t < NCHUNK; ++t) {
        // write chunk t (drain of its loads happens HERE via data dep,
        // i.e. after chunk t-1's full compute phase — latency hidden)
        float4* bufp = &lds[t & 1][0][0][0];
        #pragma unroll
        for (int i = 0; i < PER - 1; ++i) bufp[ldst[i]] = stg[i];
        if (svalid5) bufp[ldst[PER - 1]] = stg[PER - 1];

        __syncthreads();   // writes visible; buf[t&1] readers (t-2) long done

        if (t + 1 < NCHUNK) {                 // issue next chunk AFTER barrier
            const float* nb = in1b + (size_t)(t + 1) * KC * plane;
            #pragma unroll
            for (int i = 0; i < PER; ++i)
                stg[i] = sok[i] ? *(const float4*)(nb + soff[i])
                                : make_float4(0.f, 0.f, 0.f, 0.f);
        }

        #pragma unroll
        for (int ch = 0; ch < KC; ++ch) {
            const float* pac = pa + (size_t)(t * KC + ch) * plane;
            const float4 a0 = *(const float4*)(pac + 0);
            const float4 a1 = *(const float4*)(pac + 4);
            const float4 a2 = *(const float4*)(pac + 8);
            const float av[WPT] = {a0.x, a0.y, a0.z, a0.w,
                                   a1.x, a1.y, a1.z, a1.w,
                                   a2.x, a2.y, a2.z, a2.w};
            const float4* rbase = &lds[t & 1][ch][rowidx][0];
            float wn[20];
            #pragma unroll
            for (int k = 0; k < 5; ++k) {
                const float4 w4 = rbase[js_[k]];
                wn[4 * k + 0] = w4.x; wn[4 * k + 1] = w4.y;
                wn[4 * k + 2] = w4.z; wn[4 * k + 3] = w4.w;
            }
            #pragma unroll
            for (int cc = 0; cc < 9; ++cc)
                #pragma unroll
                for (int j = 0; j < WPT; ++j)
                    acc[cc][j] = fmaf(av[j], wn[cc + j], acc[cc][j]);
        }
    }

    // ---- epilogue: atomic accumulate the C-half partial ----
    const float scale = 1.0f / CCH;
    float* ob = out + ((size_t)b * 81 + (size_t)rr * 9) * plane
                    + (size_t)(h0 + g) * WW + (w0 + q * WPT);
    #pragma unroll
    for (int cc = 0; cc < 9; ++cc) {
        float* oc = ob + (size_t)cc * plane;
        #pragma unroll
        for (int k = 0; k < WPT; ++k)
            unsafeAtomicAdd(oc + k, acc[cc][k] * scale);
    }
}

extern "C" void kernel_launch(void* const* d_in, const int* in_sizes, int n_in,
                              void* d_out, int out_size, void* d_ws, size_t ws_size,
                              hipStream_t stream)
{
    const float* in0 = (const float*)d_in[0];
    const float* in1 = (const float*)d_in[1];
    float* out = (float*)d_out;
    hipMemsetAsync(d_out, 0, (size_t)out_size * sizeof(float), stream);
    dim3 grid(WW / TW, HH / TH, BB * 3 * CSPLIT);   // 4 x 6 x 48 = 1152 blocks
    corr81<<<grid, dim3(NTHR), 0, stream>>>(in0, in1, out);
}

// Round 5
// 575.225 us; speedup vs baseline: 1.7687x; 1.7687x over previous
//
#include <hip/hip_runtime.h>
#include <stdint.h>

namespace {
constexpr int MD  = 4;
constexpr int BB  = 8, CCH = 128, HH = 96, WW = 192;
constexpr int TH  = 16, TW = 48, WPT = 12;      // tile 16 x 48, 12 px/thread
constexpr int KC  = 4;                           // channels per LDS chunk
constexpr int NCHUNK = CCH / KC;                 // 32 chunks
constexpr int SROWS = 18;                        // staged rows
constexpr int NJ  = 16;                          // f4 per row (64 floats: w0-8..w0+55)
constexpr int NTHR = 192;                        // 3 waves; wave = one disp row
constexpr int F4C = SROWS * NJ;                  // 288 f4 per channel
constexpr int F4K = KC * F4C;                    // 1152 per chunk
constexpr int PER = F4K / NTHR;                  // 6 slots/thread, exact
constexpr int BUF_FLOATS = KC * SROWS * NJ * 4;  // 4608 floats per buffer
}

__device__ __forceinline__ void gload16(const float* g, float* l) {
    __builtin_amdgcn_global_load_lds(
        (const __attribute__((address_space(1))) void*)g,
        (__attribute__((address_space(3))) void*)l, 16, 0, 0);
}

__global__ __launch_bounds__(NTHR, 2)
void corr81(const float* __restrict__ in0,
            const float* __restrict__ in1,
            const float* __restrict__ zp,    // >=16B of zeros (d_ws)
            float* __restrict__ out)
{
    const int tid  = threadIdx.x;
    const int wv   = tid >> 6;            // wave -> rr within rrset
    const int lane = tid & 63;
    const int g    = lane >> 2;           // h-row in tile (0..15)
    const int q    = lane & 3;            // w-group: owns w0+q*12 .. +11

    const int wt = blockIdx.x, ht = blockIdx.y, zz = blockIdx.z;
    const int b  = zz / 3, rs = zz % 3;   // rs = rrset (disp rows rs*3..rs*3+2)
    const int w0 = wt * TW, h0 = ht * TH;
    const int rr   = rs * 3 + wv;         // displacement row 0..8
    const int rmin = rs * 3 - 4;

    __shared__ float lds[2][BUF_FLOATS];  // 36.9 KB, double-buffered

    const size_t plane = (size_t)HH * WW;
    const size_t img   = (size_t)CCH * plane;
    const float* in1b  = in1 + (size_t)b * img;

    // ---- in1 staging slots: slot s -> linear LDS f4 s; global addr uses the
    // INVERSE (= same, involution) of the read swizzle (m201 both-sides rule).
    const float* gsrc[PER];
    #pragma unroll
    for (int i = 0; i < PER; ++i) {
        const int s   = tid + i * NTHR;
        const int ch  = s / F4C;
        const int rem = s % F4C;
        const int row = rem / NJ;
        const int p   = rem % NJ;                       // linear f4 pos in row
        const int jl  = (p & 8) | ((p ^ (row & 7)) & 7);// logical window column
        const int hr  = h0 + rmin + row;
        const int wc  = w0 - 8 + 4 * jl;
        const bool ok = (hr >= 0 && hr < HH && wc >= 0 && wc <= WW - 4);
        gsrc[i] = ok ? (in1b + (size_t)ch * plane + hr * WW + wc) : zp;
    }

    // read-side swizzled indices (thread-constant)
    const int rowidx = g + wv;            // staged row for this thread
    int js_[5];
    #pragma unroll
    for (int k = 0; k < 5; ++k) {
        const int jl = 3 * q + 1 + k;     // window f4: w0+12q-4 + 4k
        js_[k] = (jl & 8) | ((jl ^ (rowidx & 7)) & 7);
    }

    const float* pa = in0 + (size_t)b * img + (size_t)(h0 + g) * WW + (w0 + q * WPT);

    float acc[9][WPT];
    #pragma unroll
    for (int cc = 0; cc < 9; ++cc)
        #pragma unroll
        for (int j = 0; j < WPT; ++j) acc[cc][j] = 0.f;

    float4 aA[12], aB[12];                // in0 ping-pong (one chunk each)

    // ---- prologue: issue chunk 0 (in1 -> lds[0], in0 -> aA) ----
    #pragma unroll
    for (int i = 0; i < PER; ++i)
        gload16(gsrc[i], &lds[0][(tid + i * NTHR) * 4]);
    #pragma unroll
    for (int ch = 0; ch < KC; ++ch) {
        const float* p0 = pa + (size_t)ch * plane;
        aA[ch * 3 + 0] = *(const float4*)(p0 + 0);
        aA[ch * 3 + 1] = *(const float4*)(p0 + 4);
        aA[ch * 3 + 2] = *(const float4*)(p0 + 8);
    }

    auto body = [&](int t, float4 (&aCur)[12], float4 (&aNxt)[12],
                    float* bufCur, float* bufNxt) {
        __syncthreads();   // drains this wave's chunk-t loads (issued ~1 phase ago);
                           // all waves' compute(t-1) (readers of bufNxt) are done.
        if (t + 1 < NCHUNK) {
            const size_t coff = (size_t)(t + 1) * KC * plane;
            #pragma unroll
            for (int i = 0; i < PER; ++i) {
                const float* gp = gsrc[i];
                gload16(gp == zp ? gp : gp + coff, &bufNxt[(tid + i * NTHR) * 4]);
            }
            #pragma unroll
            for (int ch = 0; ch < KC; ++ch) {
                const float* p0 = pa + coff + (size_t)ch * plane;
                aNxt[ch * 3 + 0] = *(const float4*)(p0 + 0);
                aNxt[ch * 3 + 1] = *(const float4*)(p0 + 4);
                aNxt[ch * 3 + 2] = *(const float4*)(p0 + 8);
            }
        }
        #pragma unroll
        for (int ch = 0; ch < KC; ++ch) {
            const float av[WPT] = {
                aCur[ch*3+0].x, aCur[ch*3+0].y, aCur[ch*3+0].z, aCur[ch*3+0].w,
                aCur[ch*3+1].x, aCur[ch*3+1].y, aCur[ch*3+1].z, aCur[ch*3+1].w,
                aCur[ch*3+2].x, aCur[ch*3+2].y, aCur[ch*3+2].z, aCur[ch*3+2].w};
            const float4* rbase =
                (const float4*)(bufCur + (ch * SROWS + rowidx) * (NJ * 4));
            float wn[20];
            #pragma unroll
            for (int k = 0; k < 5; ++k) {
                const float4 w4 = rbase[js_[k]];
                wn[4*k+0] = w4.x; wn[4*k+1] = w4.y;
                wn[4*k+2] = w4.z; wn[4*k+3] = w4.w;
            }
            #pragma unroll
            for (int cc = 0; cc < 9; ++cc)
                #pragma unroll
                for (int j = 0; j < WPT; ++j)
                    acc[cc][j] = fmaf(av[j], wn[cc + j], acc[cc][j]);
        }
    };

    for (int t = 0; t < NCHUNK; t += 2) {
        body(t,     aA, aB, lds[0], lds[1]);
        body(t + 1, aB, aA, lds[1], lds[0]);
    }

    // ---- epilogue: plain stores ----
    const float scale = 1.0f / CCH;
    float* ob = out + ((size_t)b * 81 + (size_t)rr * 9) * plane
                    + (size_t)(h0 + g) * WW + (w0 + q * WPT);
    #pragma unroll
    for (int cc = 0; cc < 9; ++cc) {
        float* oc = ob + (size_t)cc * plane;
        #pragma unroll
        for (int k = 0; k < 3; ++k) {
            float4 o = make_float4(acc[cc][4*k+0] * scale, acc[cc][4*k+1] * scale,
                                   acc[cc][4*k+2] * scale, acc[cc][4*k+3] * scale);
            *(float4*)(oc + 4 * k) = o;
        }
    }
}

extern "C" void kernel_launch(void* const* d_in, const int* in_sizes, int n_in,
                              void* d_out, int out_size, void* d_ws, size_t ws_size,
                              hipStream_t stream)
{
    const float* in0 = (const float*)d_in[0];
    const float* in1 = (const float*)d_in[1];
    float* out = (float*)d_out;
    hipMemsetAsync(d_ws, 0, 256, stream);          // zero page for OOB staging
    dim3 grid(WW / TW, HH / TH, BB * 3);           // 4 x 6 x 24 = 576 blocks
    corr81<<<grid, dim3(NTHR), 0, stream>>>(in0, in1, (const float*)d_ws, out);
}

// Round 6
// 154.123 us; speedup vs baseline: 6.6014x; 3.7323x over previous
//
#include <hip/hip_runtime.h>

namespace {
constexpr int MD  = 4;
constexpr int BB  = 8, CCH = 128, HH = 96, WW = 192;
constexpr int TH  = 16, TW = 48, WPT = 12;      // tile 16 x 48, 12 px/thread
constexpr int KC  = 4;                           // channels per LDS chunk
constexpr int NCHUNK = CCH / KC;                 // 32 chunks, 32 barriers
constexpr int SROWS = 18;                        // staged rows per rrset
constexpr int NJ  = 16;                          // f4 per row (64 floats)
constexpr int NTHR = 192;                        // 3 waves; wave = one disp row
constexpr int F4C = SROWS * NJ;                  // 288 f4 per channel
constexpr int F4K = KC * F4C;                    // 1152 f4 per chunk
constexpr int PER = F4K / NTHR;                  // 6 slots/thread, exact
constexpr int BUF_FLOATS = F4K * 4;              // 4608 floats per buffer
}

__device__ __forceinline__ void gload16(const float* g, float* l) {
    __builtin_amdgcn_global_load_lds(
        (const __attribute__((address_space(1))) void*)g,
        (__attribute__((address_space(3))) void*)l, 16, 0, 0);
}

__global__ __launch_bounds__(NTHR, 2)
void corr81(const float* __restrict__ in0,
            const float* __restrict__ in1,
            const float* __restrict__ zp,    // >=16B zero page (d_ws)
            float* __restrict__ out)
{
    const int tid  = threadIdx.x;
    const int wv   = tid >> 6;            // wave -> rr within rrset
    const int lane = tid & 63;
    const int g    = lane >> 2;           // h-row in tile (0..15)
    const int q    = lane & 3;            // w-group: owns w0+q*12 .. +11

    const int wt = blockIdx.x, ht = blockIdx.y, zz = blockIdx.z;
    const int b  = zz / 3, rs = zz % 3;   // rrset = disp rows rs*3..rs*3+2
    const int w0 = wt * TW, h0 = ht * TH;
    const int rr   = rs * 3 + wv;         // displacement row 0..8
    const int rmin = rs * 3 - 4;

    __shared__ float lds[2][BUF_FLOATS];  // 36.9 KB double-buffered

    const size_t plane = (size_t)HH * WW;
    const size_t img   = (size_t)CCH * plane;
    const float* in1b  = in1 + (size_t)b * img;

    // in1 staging: linear LDS slot s=tid+i*NTHR; global source pre-swizzled
    // with the involution (j&8)|((j^row)&7) so swizzled reads see logical data.
    const float* gsrc[PER];
    #pragma unroll
    for (int i = 0; i < PER; ++i) {
        const int s   = tid + i * NTHR;
        const int ch  = s / F4C;
        const int rem = s % F4C;
        const int row = rem / NJ;
        const int p   = rem % NJ;
        const int jl  = (p & 8) | ((p ^ (row & 7)) & 7);
        const int hr  = h0 + rmin + row;
        const int wc  = w0 - 8 + 4 * jl;
        const bool ok = (hr >= 0 && hr < HH && wc >= 0 && wc <= WW - 4);
        gsrc[i] = ok ? (in1b + (size_t)ch * plane + hr * WW + wc) : zp;
    }

    // swizzled read indices (thread-constant)
    const int rowidx = g + wv;
    int js_[5];
    #pragma unroll
    for (int k = 0; k < 5; ++k) {
        const int jl = 3 * q + 1 + k;     // window f4: w0+12q-4 + 4k
        js_[k] = (jl & 8) | ((jl ^ (rowidx & 7)) & 7);
    }

    const float* pa = in0 + (size_t)b * img + (size_t)(h0 + g) * WW + (w0 + q * WPT);

    float acc[9][WPT];
    #pragma unroll
    for (int cc = 0; cc < 9; ++cc)
        #pragma unroll
        for (int j = 0; j < WPT; ++j) acc[cc][j] = 0.f;

    // prologue: issue chunk 0
    #pragma unroll
    for (int i = 0; i < PER; ++i)
        gload16(gsrc[i], &lds[0][(tid + i * NTHR) * 4]);

    for (int t = 0; t < NCHUNK; ++t) {
        __syncthreads();   // drains this wave's chunk-t loads (issued a full
                           // compute phase ago); prior readers of next buf done.
        if (t + 1 < NCHUNK) {             // issue next chunk AFTER the barrier
            const size_t coff = (size_t)(t + 1) * KC * plane;
            float* nb = &lds[(t + 1) & 1][0];
            #pragma unroll
            for (int i = 0; i < PER; ++i) {
                const float* gp = gsrc[i];
                gload16(gp == zp ? gp : gp + coff, &nb[(tid + i * NTHR) * 4]);
            }
        }

        const float* bufCur = &lds[t & 1][0];
        #pragma unroll
        for (int ch = 0; ch < KC; ++ch) {
            const float* pac = pa + (size_t)(t * KC + ch) * plane;
            const float4 a0 = *(const float4*)(pac + 0);
            const float4 a1 = *(const float4*)(pac + 4);
            const float4 a2 = *(const float4*)(pac + 8);
            const float av[WPT] = {a0.x, a0.y, a0.z, a0.w,
                                   a1.x, a1.y, a1.z, a1.w,
                                   a2.x, a2.y, a2.z, a2.w};
            const float4* rbase =
                (const float4*)(bufCur + (ch * SROWS + rowidx) * (NJ * 4));
            float wn[20];
            #pragma unroll
            for (int k = 0; k < 5; ++k) {
                const float4 w4 = rbase[js_[k]];
                wn[4*k+0] = w4.x; wn[4*k+1] = w4.y;
                wn[4*k+2] = w4.z; wn[4*k+3] = w4.w;
            }
            #pragma unroll
            for (int cc = 0; cc < 9; ++cc)
                #pragma unroll
                for (int j = 0; j < WPT; ++j)
                    acc[cc][j] = fmaf(av[j], wn[cc + j], acc[cc][j]);
        }
    }

    // epilogue: plain coalesced stores
    const float scale = 1.0f / CCH;
    float* ob = out + ((size_t)b * 81 + (size_t)rr * 9) * plane
                    + (size_t)(h0 + g) * WW + (w0 + q * WPT);
    #pragma unroll
    for (int cc = 0; cc < 9; ++cc) {
        float* oc = ob + (size_t)cc * plane;
        #pragma unroll
        for (int k = 0; k < 3; ++k) {
            float4 o = make_float4(acc[cc][4*k+0] * scale, acc[cc][4*k+1] * scale,
                                   acc[cc][4*k+2] * scale, acc[cc][4*k+3] * scale);
            *(float4*)(oc + 4 * k) = o;
        }
    }
}

extern "C" void kernel_launch(void* const* d_in, const int* in_sizes, int n_in,
                              void* d_out, int out_size, void* d_ws, size_t ws_size,
                              hipStream_t stream)
{
    const float* in0 = (const float*)d_in[0];
    const float* in1 = (const float*)d_in[1];
    float* out = (float*)d_out;
    hipMemsetAsync(d_ws, 0, 256, stream);          // zero page for OOB staging
    dim3 grid(WW / TW, HH / TH, BB * 3);           // 4 x 6 x 24 = 576 blocks
    corr81<<<grid, dim3(NTHR), 0, stream>>>(in0, in1, (const float*)d_ws, out);
}

// Round 7
// 130.604 us; speedup vs baseline: 7.7902x; 1.1801x over previous
//
#include <hip/hip_runtime.h>

namespace {
constexpr int MD  = 4;
constexpr int BB  = 8, CCH = 128, HH = 96, WW = 192;
constexpr int TH  = 16, TW = 48, WPT = 12;       // tile 16 x 48, 12 px/thread
constexpr int KC  = 2;                            // channels per chunk
constexpr int NCHUNK = CCH / KC;                  // 64 chunks
constexpr int SROWS = 18;                         // staged in1 rows
constexpr int NJ  = 16;                           // f4 per in1 row
constexpr int NTHR = 192;                         // 3 waves = one rrset
constexpr int F4C   = SROWS * NJ;                 // 288 f4 per in1 channel
constexpr int IN1F4 = KC * F4C;                   // 576 f4 per chunk
constexpr int IN0F4 = KC * TH * (TW / 4);         // 384 f4 per chunk
constexpr int BUFF4 = IN1F4 + IN0F4;              // 960 f4 = 15360 B
constexpr int NBUF  = 3;                          // triple buffer, 2-deep prefetch
}

__device__ __forceinline__ void gload16(const float* g, float* l) {
    __builtin_amdgcn_global_load_lds(
        (const __attribute__((address_space(1))) void*)g,
        (__attribute__((address_space(3))) void*)l, 16, 0, 0);
}

__global__ __launch_bounds__(NTHR, 2)
void corr81(const float* __restrict__ in0,
            const float* __restrict__ in1,
            const float* __restrict__ zp,     // >=16B zero page (d_ws)
            float* __restrict__ out)
{
    const int tid  = threadIdx.x;
    const int wv   = tid >> 6;             // wave -> rr within rrset
    const int lane = tid & 63;
    const int g    = lane >> 2;            // h-row in tile (0..15)
    const int q    = lane & 3;             // w-group: owns w0+q*12 .. +11

    const int wt = blockIdx.x, ht = blockIdx.y, zz = blockIdx.z;
    const int b  = zz / 3, rs = zz % 3;    // rrset = disp rows rs*3..rs*3+2
    const int w0 = wt * TW, h0 = ht * TH;
    const int rr   = rs * 3 + wv;
    const int rmin = rs * 3 - 4;

    __shared__ float lds[NBUF * BUFF4 * 4];   // 46.1 KB

    const size_t plane = (size_t)HH * WW;
    const size_t img   = (size_t)CCH * plane;
    const float* in1b  = in1 + (size_t)b * img;

    // ---- in1 staging (3 f4/thread/chunk): linear LDS slot, source pre-swizzled
    // with involution (j&8)|((j^row)&7)  [validated R6]
    const float* gsrc[3];
    #pragma unroll
    for (int i = 0; i < 3; ++i) {
        const int s   = tid + i * NTHR;
        const int ch  = s / F4C;                         // 0..1
        const int rem = s % F4C;
        const int row = rem / NJ;
        const int p   = rem % NJ;
        const int jl  = (p & 8) | ((p ^ (row & 7)) & 7);
        const int hr  = h0 + rmin + row;
        const int wc  = w0 - 8 + 4 * jl;
        const bool ok = (hr >= 0 && hr < HH && wc >= 0 && wc <= WW - 4);
        gsrc[i] = ok ? (in1b + (size_t)ch * plane + hr * WW + wc) : zp;
    }

    // ---- in0 staging (2 f4/thread/chunk): slot = ch*192 + tid, always in-bounds
    const float* pin0 = in0 + (size_t)b * img
                      + (size_t)(h0 + tid / 12) * WW + (w0 + (tid % 12) * 4);

    // swizzled in1 read indices (thread-constant)
    const int rowidx = g + wv;
    int js_[5];
    #pragma unroll
    for (int k = 0; k < 5; ++k) {
        const int jl = 3 * q + 1 + k;          // window f4: w0+12q-4 + 4k
        js_[k] = (jl & 8) | ((jl ^ (rowidx & 7)) & 7);
    }

    float acc[9][WPT];
    #pragma unroll
    for (int cc = 0; cc < 9; ++cc)
        #pragma unroll
        for (int j = 0; j < WPT; ++j) acc[cc][j] = 0.f;

    auto issue = [&](int u, int k) {       // stage chunk u into buffer k (5 gloads)
        float* bf = &lds[k * BUFF4 * 4];
        const size_t coff = (size_t)u * KC * plane;
        #pragma unroll
        for (int i = 0; i < 3; ++i) {
            const float* gp = gsrc[i];
            gload16(gp == zp ? gp : gp + coff, bf + (size_t)(tid + i * NTHR) * 4);
        }
        #pragma unroll
        for (int i = 0; i < 2; ++i)
            gload16(pin0 + coff + (size_t)i * plane,
                    bf + (size_t)(IN1F4 + i * NTHR + tid) * 4);
    };

    auto compute = [&](int k) {            // consume buffer k (pure LDS + FMA)
        const float* bf = &lds[k * BUFF4 * 4];
        #pragma unroll
        for (int ch = 0; ch < KC; ++ch) {
            const float4* a4 = (const float4*)(bf + (size_t)(IN1F4 + ch * NTHR
                                                    + g * 12 + 3 * q) * 4);
            const float4 a0 = a4[0], a1 = a4[1], a2 = a4[2];
            const float av[WPT] = {a0.x, a0.y, a0.z, a0.w,
                                   a1.x, a1.y, a1.z, a1.w,
                                   a2.x, a2.y, a2.z, a2.w};
            const float4* rbase =
                (const float4*)(bf + (size_t)((ch * SROWS + rowidx) * NJ) * 4);
            float wn[20];
            #pragma unroll
            for (int kk = 0; kk < 5; ++kk) {
                const float4 w4 = rbase[js_[kk]];
                wn[4*kk+0] = w4.x; wn[4*kk+1] = w4.y;
                wn[4*kk+2] = w4.z; wn[4*kk+3] = w4.w;
            }
            #pragma unroll
            for (int cc = 0; cc < 9; ++cc)
                #pragma unroll
                for (int j = 0; j < WPT; ++j)
                    acc[cc][j] = fmaf(av[j], wn[cc + j], acc[cc][j]);
        }
    };

    // ---- prologue: 2 chunks in flight ----
    issue(0, 0);
    issue(1, 1);

    int cur = 0;
    for (int t = 0; t < NCHUNK - 1; ++t) {
        __builtin_amdgcn_sched_barrier(0);
        asm volatile("s_waitcnt vmcnt(5)" ::: "memory");  // chunk t landed; t+1 stays in flight
        __builtin_amdgcn_s_barrier();
        __builtin_amdgcn_sched_barrier(0);
        if (t + 2 < NCHUNK) {
            const int fut = (cur + 2 >= NBUF) ? cur + 2 - NBUF : cur + 2;
            issue(t + 2, fut);
        }
        compute(cur);
        cur = (cur + 1 >= NBUF) ? 0 : cur + 1;
    }
    // peeled last chunk
    __builtin_amdgcn_sched_barrier(0);
    asm volatile("s_waitcnt vmcnt(0)" ::: "memory");
    __builtin_amdgcn_s_barrier();
    __builtin_amdgcn_sched_barrier(0);
    compute(cur);

    // ---- epilogue: plain coalesced stores ----
    const float scale = 1.0f / CCH;
    float* ob = out + ((size_t)b * 81 + (size_t)rr * 9) * plane
                    + (size_t)(h0 + g) * WW + (w0 + q * WPT);
    #pragma unroll
    for (int cc = 0; cc < 9; ++cc) {
        float* oc = ob + (size_t)cc * plane;
        #pragma unroll
        for (int k = 0; k < 3; ++k) {
            float4 o = make_float4(acc[cc][4*k+0] * scale, acc[cc][4*k+1] * scale,
                                   acc[cc][4*k+2] * scale, acc[cc][4*k+3] * scale);
            *(float4*)(oc + 4 * k) = o;
        }
    }
}

extern "C" void kernel_launch(void* const* d_in, const int* in_sizes, int n_in,
                              void* d_out, int out_size, void* d_ws, size_t ws_size,
                              hipStream_t stream)
{
    const float* in0 = (const float*)d_in[0];
    const float* in1 = (const float*)d_in[1];
    float* out = (float*)d_out;
    hipMemsetAsync(d_ws, 0, 256, stream);          // zero page for OOB staging
    dim3 grid(WW / TW, HH / TH, BB * 3);           // 4 x 6 x 24 = 576 blocks
    corr81<<<grid, dim3(NTHR), 0, stream>>>(in0, in1, (const float*)d_ws, out);
}